// Round 5
// baseline (664.610 us; speedup 1.0000x reference)
//
#include <hip/hip_runtime.h>

typedef unsigned short USHORT;
typedef short bf16x8 __attribute__((ext_vector_type(8)));
typedef float f32x4 __attribute__((ext_vector_type(4)));

__device__ __forceinline__ USHORT f2bf(float f) {
    unsigned u = __float_as_uint(f);
    u += 0x7fffu + ((u >> 16) & 1u);   // RNE, no NaNs in this problem
    return (USHORT)(u >> 16);
}
__device__ __forceinline__ float bf2f(USHORT s) {
    return __uint_as_float(((unsigned)s) << 16);
}
__device__ __forceinline__ float sigm(float v) { return 1.f / (1.f + __expf(-v)); }
__device__ __forceinline__ float mytanh(float v) { return 1.f - 2.f / (__expf(2.f * v) + 1.f); }

using gcu32p = const unsigned int __attribute__((address_space(1))) *;
using lu32p  = unsigned int __attribute__((address_space(3))) *;

__device__ __forceinline__ void load_lds16(const void* g, void* l) {
    __builtin_amdgcn_global_load_lds((gcu32p)g, (lu32p)l, 16, 0, 0);
}

// ---- single conversion kernel: fp32 sources -> bf16 A [8192x4096] and W [3072x4096]
__global__ __launch_bounds__(256) void conv_all(const float* __restrict__ h,
                                                const float* __restrict__ x,
                                                const float* __restrict__ glo,
                                                const float* __restrict__ Wi,
                                                const float* __restrict__ Wf,
                                                const float* __restrict__ Wc,
                                                USHORT* __restrict__ A,
                                                USHORT* __restrict__ W) {
    int bid = blockIdx.x;
    if (bid < 16384) {
        int idx = (bid * 256 + threadIdx.x) * 8;      // [0, 8192*4096)
        int m = idx >> 12, k = idx & 4095;
        const float* s;
        if (k < 1024)      s = h   + (size_t)m * 1024 + k;
        else if (k < 3072) s = x   + (size_t)m * 2048 + (k - 1024);
        else               s = glo + (size_t)m * 1024 + (k - 3072);
        float4 f0 = ((const float4*)s)[0];
        float4 f1 = ((const float4*)s)[1];
        union { USHORT us[8]; uint4 v; } u;
        u.us[0] = f2bf(f0.x); u.us[1] = f2bf(f0.y); u.us[2] = f2bf(f0.z); u.us[3] = f2bf(f0.w);
        u.us[4] = f2bf(f1.x); u.us[5] = f2bf(f1.y); u.us[6] = f2bf(f1.z); u.us[7] = f2bf(f1.w);
        *(uint4*)(A + idx) = u.v;
    } else {
        int idx = ((bid - 16384) * 256 + threadIdx.x) * 8;   // [0, 3072*4096)
        int n = idx >> 12, k = idx & 4095;
        const float* base = (n < 1024) ? Wi : (n < 2048 ? Wf : Wc);
        const float* s = base + (size_t)(n & 1023) * 4096 + k;
        float4 f0 = ((const float4*)s)[0];
        float4 f1 = ((const float4*)s)[1];
        union { USHORT us[8]; uint4 v; } u;
        u.us[0] = f2bf(f0.x); u.us[1] = f2bf(f0.y); u.us[2] = f2bf(f0.z); u.us[3] = f2bf(f0.w);
        u.us[4] = f2bf(f1.x); u.us[5] = f2bf(f1.y); u.us[6] = f2bf(f1.z); u.us[7] = f2bf(f1.w);
        *(uint4*)(W + idx) = u.v;
    }
}

// ---- fused GEMM+epilogue: block tile = 128 m-rows x 64 h-cols x {i,f,c} gates.
// A-tile 128x32 (8KB), B-tile 192x32 (12KB, rows = Wi|Wf|Wc for the 64 cols).
// 4 waves in 2x2 (wave: 64m x 32cols per gate); per wave 4x(2x3) 16x16x32 MFMA.
// XOR-swizzled LDS (verified 0-conflict round 4). Output written directly.
__global__ __launch_bounds__(256) void gemm2(const USHORT* __restrict__ A,
                                             const USHORT* __restrict__ B,
                                             const float* __restrict__ h,
                                             const float* __restrict__ bi,
                                             const float* __restrict__ bfp,
                                             const float* __restrict__ bc,
                                             float* __restrict__ out) {
    __shared__ USHORT At[128 * 32];
    __shared__ USHORT Bt[192 * 32];

    const int tid  = threadIdx.x;
    const int lane = tid & 63, wv = tid >> 6;
    const int n0 = blockIdx.x * 64;       // h-column tile (0..1023)
    const int m0 = blockIdx.y * 128;      // row tile
    const int wM = wv >> 1, wN = wv & 1;
    const int lm = lane & 15;
    const int gw = lane >> 4;                       // wanted k-granule (0..3)
    const int swz8 = (gw ^ ((lm >> 1) & 3)) * 8;    // swizzled granule offset

    // staging: rows rS..rS of a 16-row chunk; lane fetches global granule gS so
    // that LDS position g holds global granule g ^ ((r>>1)&3).
    const int rS = wv * 16 + (lane >> 2);           // [0,64)
    const int gS = (lane & 3) ^ ((rS >> 1) & 3);
    USHORT* lA0 = At + wv * 512;
    USHORT* lA1 = At + (4 + wv) * 512;
    USHORT* lB0 = Bt + wv * 512;
    USHORT* lB1 = Bt + (4 + wv) * 512;
    USHORT* lB2 = Bt + (8 + wv) * 512;

    const USHORT* a0 = A + (size_t)(m0 + rS) * 4096 + gS * 8;
    const USHORT* a1 = A + (size_t)(m0 + rS + 64) * 4096 + gS * 8;
    const USHORT* b0 = B + (size_t)(n0 + rS) * 4096 + gS * 8;          // Wi rows
    const USHORT* b1 = b0 + (size_t)1024 * 4096;                       // Wf rows
    const USHORT* b2 = b0 + (size_t)2048 * 4096;                       // Wc rows

    f32x4 acc[4][6];   // [m-tile][gate*2 + n-tile]
    #pragma unroll
    for (int a = 0; a < 4; ++a)
        #pragma unroll
        for (int b = 0; b < 6; ++b) {
            f32x4 z = {0.f, 0.f, 0.f, 0.f};
            acc[a][b] = z;
        }

    for (int kt = 0; kt < 128; ++kt) {
        __syncthreads();
        load_lds16(a0, lA0);
        load_lds16(a1, lA1);
        load_lds16(b0, lB0);
        load_lds16(b1, lB1);
        load_lds16(b2, lB2);
        a0 += 32; a1 += 32; b0 += 32; b1 += 32; b2 += 32;
        __syncthreads();

        bf16x8 av[4], bv[6];
        #pragma unroll
        for (int mt = 0; mt < 4; ++mt)
            av[mt] = *(const bf16x8*)(At + (wM * 64 + mt * 16 + lm) * 32 + swz8);
        #pragma unroll
        for (int g = 0; g < 3; ++g)
            #pragma unroll
            for (int nt = 0; nt < 2; ++nt)
                bv[g * 2 + nt] = *(const bf16x8*)(Bt + (g * 64 + wN * 32 + nt * 16 + lm) * 32 + swz8);
        #pragma unroll
        for (int mt = 0; mt < 4; ++mt)
            #pragma unroll
            for (int q = 0; q < 6; ++q)
                acc[mt][q] = __builtin_amdgcn_mfma_f32_16x16x32_bf16(
                    av[mt], bv[q], acc[mt][q], 0, 0, 0);
    }

    // fused epilogue: i,f,c for (row,col) live in the same lane/reg slot.
    // C/D: col = lane&15, row = (lane>>4)*4 + r.
    #pragma unroll
    for (int nt = 0; nt < 2; ++nt) {
        int lcol = wN * 32 + nt * 16 + lm;
        int col  = n0 + lcol;
        float bbi = bi[col], bbf = bfp[col], bbc = bc[col];
        #pragma unroll
        for (int mt = 0; mt < 4; ++mt) {
            #pragma unroll
            for (int r = 0; r < 4; ++r) {
                int lrow = wM * 64 + mt * 16 + (lane >> 4) * 4 + r;
                size_t gidx = (size_t)(m0 + lrow) * 1024 + col;
                float iv = sigm(acc[mt][0 + nt][r] + bbi);
                float fv = sigm(acc[mt][2 + nt][r] + bbf);
                float cv = mytanh(acc[mt][4 + nt][r] + bbc);
                float al = sigm(iv - fv);
                out[gidx] = al * cv + (1.f - al) * h[gidx];
            }
        }
    }
}

// ---- fallback: fused 3-phase kernel (only if ws too small; known-good)
__global__ __launch_bounds__(256) void gemm3_noconv(const float* __restrict__ h,
                                                    const float* __restrict__ x,
                                                    const float* __restrict__ glo,
                                                    const float* __restrict__ Wi,
                                                    const float* __restrict__ Wf,
                                                    const float* __restrict__ Wc,
                                                    const float* __restrict__ bi,
                                                    const float* __restrict__ bfp,
                                                    const float* __restrict__ bc,
                                                    float* __restrict__ out) {
    __shared__ USHORT At[128 * 32];
    __shared__ USHORT Bt[128 * 32];
    __shared__ USHORT stash[128 * 136];

    const int tid  = threadIdx.x;
    const int lane = tid & 63, wv = tid >> 6;
    const int n0 = blockIdx.x * 128;
    const int m0 = blockIdx.y * 128;
    const int wM = wv >> 1, wN = wv & 1;
    const int lm = lane & 15, qk = (lane >> 4) * 8;
    const int rowS = tid >> 1;
    const int colS = (tid & 1) * 16;

    for (int p = 0; p < 3; ++p) {
        f32x4 acc[4][4];
        #pragma unroll
        for (int a = 0; a < 4; ++a)
            #pragma unroll
            for (int b = 0; b < 4; ++b) {
                f32x4 z = {0.f, 0.f, 0.f, 0.f};
                acc[a][b] = z;
            }
        const float* Wg = (p == 0) ? Wi : (p == 1 ? Wf : Wc);

        for (int kt = 0; kt < 128; ++kt) {
            __syncthreads();
            int k = kt * 32 + colS;
            const float* s;
            if (k < 1024)      s = h   + (size_t)(m0 + rowS) * 1024 + k;
            else if (k < 3072) s = x   + (size_t)(m0 + rowS) * 2048 + (k - 1024);
            else               s = glo + (size_t)(m0 + rowS) * 1024 + (k - 3072);
            float4 f0 = ((const float4*)s)[0], f1 = ((const float4*)s)[1];
            float4 f2 = ((const float4*)s)[2], f3 = ((const float4*)s)[3];
            union { USHORT us[8]; uint4 v; } u0, u1;
            u0.us[0]=f2bf(f0.x); u0.us[1]=f2bf(f0.y); u0.us[2]=f2bf(f0.z); u0.us[3]=f2bf(f0.w);
            u0.us[4]=f2bf(f1.x); u0.us[5]=f2bf(f1.y); u0.us[6]=f2bf(f1.z); u0.us[7]=f2bf(f1.w);
            u1.us[0]=f2bf(f2.x); u1.us[1]=f2bf(f2.y); u1.us[2]=f2bf(f2.z); u1.us[3]=f2bf(f2.w);
            u1.us[4]=f2bf(f3.x); u1.us[5]=f2bf(f3.y); u1.us[6]=f2bf(f3.z); u1.us[7]=f2bf(f3.w);
            *(uint4*)(At + rowS * 32 + colS)     = u0.v;
            *(uint4*)(At + rowS * 32 + colS + 8) = u1.v;
            const float* sw = Wg + (size_t)(n0 + rowS) * 4096 + k;
            float4 w0 = ((const float4*)sw)[0], w1 = ((const float4*)sw)[1];
            float4 w2 = ((const float4*)sw)[2], w3 = ((const float4*)sw)[3];
            union { USHORT us[8]; uint4 v; } v0, v1;
            v0.us[0]=f2bf(w0.x); v0.us[1]=f2bf(w0.y); v0.us[2]=f2bf(w0.z); v0.us[3]=f2bf(w0.w);
            v0.us[4]=f2bf(w1.x); v0.us[5]=f2bf(w1.y); v0.us[6]=f2bf(w1.z); v0.us[7]=f2bf(w1.w);
            v1.us[0]=f2bf(w2.x); v1.us[1]=f2bf(w2.y); v1.us[2]=f2bf(w2.z); v1.us[3]=f2bf(w2.w);
            v1.us[4]=f2bf(w3.x); v1.us[5]=f2bf(w3.y); v1.us[6]=f2bf(w3.z); v1.us[7]=f2bf(w3.w);
            *(uint4*)(Bt + rowS * 32 + colS)     = v0.v;
            *(uint4*)(Bt + rowS * 32 + colS + 8) = v1.v;
            __syncthreads();

            bf16x8 av[4], bv[4];
            #pragma unroll
            for (int mt = 0; mt < 4; ++mt)
                av[mt] = *(const bf16x8*)(At + (wM * 64 + mt * 16 + lm) * 32 + qk);
            #pragma unroll
            for (int nt = 0; nt < 4; ++nt)
                bv[nt] = *(const bf16x8*)(Bt + (wN * 64 + nt * 16 + lm) * 32 + qk);
            #pragma unroll
            for (int mt = 0; mt < 4; ++mt)
                #pragma unroll
                for (int nt = 0; nt < 4; ++nt)
                    acc[mt][nt] = __builtin_amdgcn_mfma_f32_16x16x32_bf16(
                        av[mt], bv[nt], acc[mt][nt], 0, 0, 0);
        }

        const float* bias = (p == 0) ? bi : (p == 1 ? bfp : bc);
        #pragma unroll
        for (int nt = 0; nt < 4; ++nt) {
            int lcol = wN * 64 + nt * 16 + lm;
            float bb = bias[n0 + lcol];
            #pragma unroll
            for (int mt = 0; mt < 4; ++mt) {
                #pragma unroll
                for (int r = 0; r < 4; ++r) {
                    int lrow = wM * 64 + mt * 16 + (lane >> 4) * 4 + r;
                    float g = acc[mt][nt][r] + bb;
                    int li = lrow * 136 + lcol;
                    if (p == 0) {
                        stash[li] = f2bf(sigm(g));
                    } else if (p == 1) {
                        float iv = bf2f(stash[li]);
                        stash[li] = f2bf(sigm(iv - sigm(g)));
                    } else {
                        float al = bf2f(stash[li]);
                        float cv = mytanh(g);
                        size_t gi = (size_t)(m0 + lrow) * 1024 + (n0 + lcol);
                        out[gi] = al * cv + (1.f - al) * h[gi];
                    }
                }
            }
        }
    }
}

extern "C" void kernel_launch(void* const* d_in, const int* in_sizes, int n_in,
                              void* d_out, int out_size, void* d_ws, size_t ws_size,
                              hipStream_t stream) {
    const float* h   = (const float*)d_in[0];
    const float* x   = (const float*)d_in[1];
    const float* glo = (const float*)d_in[2];
    const float* Wi  = (const float*)d_in[3];
    const float* bi  = (const float*)d_in[4];
    const float* Wf  = (const float*)d_in[5];
    const float* bfp = (const float*)d_in[6];
    const float* Wc  = (const float*)d_in[7];
    const float* bc  = (const float*)d_in[8];
    float* out = (float*)d_out;

    const size_t szA = (size_t)8192 * 4096 * 2;   // 64 MiB bf16 A
    const size_t szW = (size_t)3072 * 4096 * 2;   // 24 MiB bf16 W

    if (ws_size >= szA + szW) {
        USHORT* Abf = (USHORT*)d_ws;
        USHORT* Wbf = (USHORT*)((char*)d_ws + szA);
        conv_all<<<16384 + 6144, 256, 0, stream>>>(h, x, glo, Wi, Wf, Wc, Abf, Wbf);
        gemm2<<<dim3(16, 64), 256, 0, stream>>>(Abf, Wbf, h, bi, bfp, bc, out);
    } else {
        gemm3_noconv<<<dim3(8, 64), 256, 0, stream>>>(
            h, x, glo, Wi, Wf, Wc, bi, bfp, bc, out);
    }
}

// Round 6
// 423.646 us; speedup vs baseline: 1.5688x; 1.5688x over previous
//
#include <hip/hip_runtime.h>

typedef unsigned short USHORT;
typedef short bf16x8 __attribute__((ext_vector_type(8)));
typedef float f32x4 __attribute__((ext_vector_type(4)));

__device__ __forceinline__ USHORT f2bf(float f) {
    unsigned u = __float_as_uint(f);
    u += 0x7fffu + ((u >> 16) & 1u);   // RNE, no NaNs in this problem
    return (USHORT)(u >> 16);
}
__device__ __forceinline__ float bf2f(USHORT s) {
    return __uint_as_float(((unsigned)s) << 16);
}
__device__ __forceinline__ float sigm(float v) { return 1.f / (1.f + __expf(-v)); }
__device__ __forceinline__ float mytanh(float v) { return 1.f - 2.f / (__expf(2.f * v) + 1.f); }

using gcu32p = const unsigned int __attribute__((address_space(1))) *;
using lu32p  = unsigned int __attribute__((address_space(3))) *;

__device__ __forceinline__ void load_lds16(const void* g, void* l) {
    __builtin_amdgcn_global_load_lds((gcu32p)g, (lu32p)l, 16, 0, 0);
}

// ---- single conversion kernel: fp32 sources -> bf16 A [8192x4096] and W [3072x4096]
__global__ __launch_bounds__(256) void conv_all(const float* __restrict__ h,
                                                const float* __restrict__ x,
                                                const float* __restrict__ glo,
                                                const float* __restrict__ Wi,
                                                const float* __restrict__ Wf,
                                                const float* __restrict__ Wc,
                                                USHORT* __restrict__ A,
                                                USHORT* __restrict__ W) {
    int bid = blockIdx.x;
    if (bid < 16384) {
        int idx = (bid * 256 + threadIdx.x) * 8;      // [0, 8192*4096)
        int m = idx >> 12, k = idx & 4095;
        const float* s;
        if (k < 1024)      s = h   + (size_t)m * 1024 + k;
        else if (k < 3072) s = x   + (size_t)m * 2048 + (k - 1024);
        else               s = glo + (size_t)m * 1024 + (k - 3072);
        float4 f0 = ((const float4*)s)[0];
        float4 f1 = ((const float4*)s)[1];
        union { USHORT us[8]; uint4 v; } u;
        u.us[0] = f2bf(f0.x); u.us[1] = f2bf(f0.y); u.us[2] = f2bf(f0.z); u.us[3] = f2bf(f0.w);
        u.us[4] = f2bf(f1.x); u.us[5] = f2bf(f1.y); u.us[6] = f2bf(f1.z); u.us[7] = f2bf(f1.w);
        *(uint4*)(A + idx) = u.v;
    } else {
        int idx = ((bid - 16384) * 256 + threadIdx.x) * 8;   // [0, 3072*4096)
        int n = idx >> 12, k = idx & 4095;
        const float* base = (n < 1024) ? Wi : (n < 2048 ? Wf : Wc);
        const float* s = base + (size_t)(n & 1023) * 4096 + k;
        float4 f0 = ((const float4*)s)[0];
        float4 f1 = ((const float4*)s)[1];
        union { USHORT us[8]; uint4 v; } u;
        u.us[0] = f2bf(f0.x); u.us[1] = f2bf(f0.y); u.us[2] = f2bf(f0.z); u.us[3] = f2bf(f0.w);
        u.us[4] = f2bf(f1.x); u.us[5] = f2bf(f1.y); u.us[6] = f2bf(f1.z); u.us[7] = f2bf(f1.w);
        *(uint4*)(W + idx) = u.v;
    }
}

// ---- GEMM: gates[8192,3072] = A[8192,4096] @ W[3072,4096]^T + bias, bf16 out.
// 128x128 tile, BK=64 (half the barriers of BK=32), 4 waves 2x2, 4x4 16x16x32 MFMA.
// LDS granule swizzle: pos p (16B granule) of row r holds global granule
// p ^ ((r>>1)&7) -> ds_read_b128 spreads 8 lanes per 4-bank group = conflict-free.
__global__ __launch_bounds__(256) void gemm_bt(const USHORT* __restrict__ A,
                                               const USHORT* __restrict__ B,
                                               const float* __restrict__ bi,
                                               const float* __restrict__ bfp,
                                               const float* __restrict__ bc,
                                               USHORT* __restrict__ gates) {
    __shared__ USHORT At[128 * 64];
    __shared__ USHORT Bt[128 * 64];

    const int tid  = threadIdx.x;
    const int lane = tid & 63, wv = tid >> 6;
    const int bx = blockIdx.x;            // 0..23 over gate cols
    const int n0 = bx * 128;
    const int m0 = blockIdx.y * 128;
    const int wM = wv >> 1, wN = wv & 1;
    const int lm = lane & 15;
    const int gw = lane >> 4;                       // wanted k-granule within 32-half
    // swizzled granule offsets (elements) for the two 32-el k-halves:
    const int swz0 = (((0 * 4 + gw) ^ (lm >> 1)) & 7) * 8;
    const int swz1 = (((1 * 4 + gw) ^ (lm >> 1)) & 7) * 8;

    // staging: 16 chunks of 8 rows x 64 el; wave wv takes chunks wv, wv+4, wv+8, wv+12.
    // lane l -> row r = c*8 + (l>>3), LDS pos p = l&7, fetch global granule p^((r>>1)&7).
    const USHORT* aP[4];
    const USHORT* bP[4];
    USHORT* lA[4];
    USHORT* lB[4];
    #pragma unroll
    for (int j = 0; j < 4; ++j) {
        int c = wv + j * 4;
        int r = c * 8 + (lane >> 3);
        int g = (lane & 7) ^ ((r >> 1) & 7);
        lA[j] = At + c * 512;
        lB[j] = Bt + c * 512;
        aP[j] = A + (size_t)(m0 + r) * 4096 + g * 8;
        bP[j] = B + (size_t)(n0 + r) * 4096 + g * 8;
    }

    f32x4 acc[4][4];
    #pragma unroll
    for (int a = 0; a < 4; ++a)
        #pragma unroll
        for (int b = 0; b < 4; ++b) {
            f32x4 z = {0.f, 0.f, 0.f, 0.f};
            acc[a][b] = z;
        }

    for (int kt = 0; kt < 64; ++kt) {
        __syncthreads();
        #pragma unroll
        for (int j = 0; j < 4; ++j) load_lds16(aP[j], lA[j]);
        #pragma unroll
        for (int j = 0; j < 4; ++j) load_lds16(bP[j], lB[j]);
        #pragma unroll
        for (int j = 0; j < 4; ++j) { aP[j] += 64; bP[j] += 64; }
        __syncthreads();

        #pragma unroll
        for (int kh = 0; kh < 2; ++kh) {
            const int swz = kh ? swz1 : swz0;
            bf16x8 av[4], bv[4];
            #pragma unroll
            for (int mt = 0; mt < 4; ++mt)
                av[mt] = *(const bf16x8*)(At + (wM * 64 + mt * 16 + lm) * 64 + swz);
            #pragma unroll
            for (int nt = 0; nt < 4; ++nt)
                bv[nt] = *(const bf16x8*)(Bt + (wN * 64 + nt * 16 + lm) * 64 + swz);
            #pragma unroll
            for (int mt = 0; mt < 4; ++mt)
                #pragma unroll
                for (int nt = 0; nt < 4; ++nt)
                    acc[mt][nt] = __builtin_amdgcn_mfma_f32_16x16x32_bf16(
                        av[mt], bv[nt], acc[mt][nt], 0, 0, 0);
        }
    }

    // epilogue: +bias, store bf16 gates. C/D: col = lane&15, row = (lane>>4)*4 + r.
    const float* bias = (bx < 8) ? bi : (bx < 16 ? bfp : bc);
    const int boff = (bx & 7) * 128;
    #pragma unroll
    for (int nt = 0; nt < 4; ++nt) {
        int lcol = wN * 64 + nt * 16 + lm;
        float bb = bias[boff + lcol];
        #pragma unroll
        for (int mt = 0; mt < 4; ++mt) {
            #pragma unroll
            for (int r = 0; r < 4; ++r) {
                int lrow = wM * 64 + mt * 16 + (lane >> 4) * 4 + r;
                gates[(size_t)(m0 + lrow) * 3072 + n0 + lcol] = f2bf(acc[mt][nt][r] + bb);
            }
        }
    }
}

// ---- elementwise epilogue: out = alpha*c + (1-alpha)*h
__global__ __launch_bounds__(256) void epi(const USHORT* __restrict__ gates,
                                           const float* __restrict__ h,
                                           float* __restrict__ out) {
    int e = (blockIdx.x * 256 + threadIdx.x) * 8;   // [0, 8192*1024)
    int m = e >> 10, n = e & 1023;
    const USHORT* gp = gates + (size_t)m * 3072 + n;
    union { USHORT us[8]; uint4 v; } gi, gf, gc;
    gi.v = *(const uint4*)(gp);
    gf.v = *(const uint4*)(gp + 1024);
    gc.v = *(const uint4*)(gp + 2048);
    const float* hp = h + (size_t)m * 1024 + n;
    float4 h0 = ((const float4*)hp)[0];
    float4 h1 = ((const float4*)hp)[1];
    float hv[8] = {h0.x, h0.y, h0.z, h0.w, h1.x, h1.y, h1.z, h1.w};
    float o[8];
    #pragma unroll
    for (int j = 0; j < 8; ++j) {
        float iv = sigm(bf2f(gi.us[j]));
        float fv = sigm(bf2f(gf.us[j]));
        float cv = mytanh(bf2f(gc.us[j]));
        float al = sigm(iv - fv);
        o[j] = al * cv + (1.f - al) * hv[j];
    }
    float4* op = (float4*)(out + (size_t)m * 1024 + n);
    op[0] = make_float4(o[0], o[1], o[2], o[3]);
    op[1] = make_float4(o[4], o[5], o[6], o[7]);
}

// ---- fallback: fused 3-phase kernel, register-convert staging (only if ws too small)
__global__ __launch_bounds__(256) void gemm3_noconv(const float* __restrict__ h,
                                                    const float* __restrict__ x,
                                                    const float* __restrict__ glo,
                                                    const float* __restrict__ Wi,
                                                    const float* __restrict__ Wf,
                                                    const float* __restrict__ Wc,
                                                    const float* __restrict__ bi,
                                                    const float* __restrict__ bfp,
                                                    const float* __restrict__ bc,
                                                    float* __restrict__ out) {
    __shared__ USHORT At[128 * 32];
    __shared__ USHORT Bt[128 * 32];
    __shared__ USHORT stash[128 * 136];

    const int tid  = threadIdx.x;
    const int lane = tid & 63, wv = tid >> 6;
    const int n0 = blockIdx.x * 128;
    const int m0 = blockIdx.y * 128;
    const int wM = wv >> 1, wN = wv & 1;
    const int lm = lane & 15, qk = (lane >> 4) * 8;
    const int rowS = tid >> 1;
    const int colS = (tid & 1) * 16;

    for (int p = 0; p < 3; ++p) {
        f32x4 acc[4][4];
        #pragma unroll
        for (int a = 0; a < 4; ++a)
            #pragma unroll
            for (int b = 0; b < 4; ++b) {
                f32x4 z = {0.f, 0.f, 0.f, 0.f};
                acc[a][b] = z;
            }
        const float* Wg = (p == 0) ? Wi : (p == 1 ? Wf : Wc);

        for (int kt = 0; kt < 128; ++kt) {
            __syncthreads();
            int k = kt * 32 + colS;
            const float* s;
            if (k < 1024)      s = h   + (size_t)(m0 + rowS) * 1024 + k;
            else if (k < 3072) s = x   + (size_t)(m0 + rowS) * 2048 + (k - 1024);
            else               s = glo + (size_t)(m0 + rowS) * 1024 + (k - 3072);
            float4 f0 = ((const float4*)s)[0], f1 = ((const float4*)s)[1];
            float4 f2 = ((const float4*)s)[2], f3 = ((const float4*)s)[3];
            union { USHORT us[8]; uint4 v; } u0, u1;
            u0.us[0]=f2bf(f0.x); u0.us[1]=f2bf(f0.y); u0.us[2]=f2bf(f0.z); u0.us[3]=f2bf(f0.w);
            u0.us[4]=f2bf(f1.x); u0.us[5]=f2bf(f1.y); u0.us[6]=f2bf(f1.z); u0.us[7]=f2bf(f1.w);
            u1.us[0]=f2bf(f2.x); u1.us[1]=f2bf(f2.y); u1.us[2]=f2bf(f2.z); u1.us[3]=f2bf(f2.w);
            u1.us[4]=f2bf(f3.x); u1.us[5]=f2bf(f3.y); u1.us[6]=f2bf(f3.z); u1.us[7]=f2bf(f3.w);
            *(uint4*)(At + rowS * 32 + colS)     = u0.v;
            *(uint4*)(At + rowS * 32 + colS + 8) = u1.v;
            const float* sw = Wg + (size_t)(n0 + rowS) * 4096 + k;
            float4 w0 = ((const float4*)sw)[0], w1 = ((const float4*)sw)[1];
            float4 w2 = ((const float4*)sw)[2], w3 = ((const float4*)sw)[3];
            union { USHORT us[8]; uint4 v; } v0, v1;
            v0.us[0]=f2bf(w0.x); v0.us[1]=f2bf(w0.y); v0.us[2]=f2bf(w0.z); v0.us[3]=f2bf(w0.w);
            v0.us[4]=f2bf(w1.x); v0.us[5]=f2bf(w1.y); v0.us[6]=f2bf(w1.z); v0.us[7]=f2bf(w1.w);
            v1.us[0]=f2bf(w2.x); v1.us[1]=f2bf(w2.y); v1.us[2]=f2bf(w2.z); v1.us[3]=f2bf(w2.w);
            v1.us[4]=f2bf(w3.x); v1.us[5]=f2bf(w3.y); v1.us[6]=f2bf(w3.z); v1.us[7]=f2bf(w3.w);
            *(uint4*)(Bt + rowS * 32 + colS)     = v0.v;
            *(uint4*)(Bt + rowS * 32 + colS + 8) = v1.v;
            __syncthreads();

            bf16x8 av[4], bv[4];
            #pragma unroll
            for (int mt = 0; mt < 4; ++mt)
                av[mt] = *(const bf16x8*)(At + (wM * 64 + mt * 16 + lm) * 32 + qk);
            #pragma unroll
            for (int nt = 0; nt < 4; ++nt)
                bv[nt] = *(const bf16x8*)(Bt + (wN * 64 + nt * 16 + lm) * 32 + qk);
            #pragma unroll
            for (int mt = 0; mt < 4; ++mt)
                #pragma unroll
                for (int nt = 0; nt < 4; ++nt)
                    acc[mt][nt] = __builtin_amdgcn_mfma_f32_16x16x32_bf16(
                        av[mt], bv[nt], acc[mt][nt], 0, 0, 0);
        }

        const float* bias = (p == 0) ? bi : (p == 1 ? bfp : bc);
        #pragma unroll
        for (int nt = 0; nt < 4; ++nt) {
            int lcol = wN * 64 + nt * 16 + lm;
            float bb = bias[n0 + lcol];
            #pragma unroll
            for (int mt = 0; mt < 4; ++mt) {
                #pragma unroll
                for (int r = 0; r < 4; ++r) {
                    int lrow = wM * 64 + mt * 16 + (lane >> 4) * 4 + r;
                    float g = acc[mt][nt][r] + bb;
                    int li = lrow * 136 + lcol;
                    if (p == 0) {
                        stash[li] = f2bf(sigm(g));
                    } else if (p == 1) {
                        float iv = bf2f(stash[li]);
                        stash[li] = f2bf(sigm(iv - sigm(g)));
                    } else {
                        float al = bf2f(stash[li]);
                        float cv = mytanh(g);
                        size_t gi = (size_t)(m0 + lrow) * 1024 + (n0 + lcol);
                        out[gi] = al * cv + (1.f - al) * h[gi];
                    }
                }
            }
        }
    }
}

extern "C" void kernel_launch(void* const* d_in, const int* in_sizes, int n_in,
                              void* d_out, int out_size, void* d_ws, size_t ws_size,
                              hipStream_t stream) {
    const float* h   = (const float*)d_in[0];
    const float* x   = (const float*)d_in[1];
    const float* glo = (const float*)d_in[2];
    const float* Wi  = (const float*)d_in[3];
    const float* bi  = (const float*)d_in[4];
    const float* Wf  = (const float*)d_in[5];
    const float* bfp = (const float*)d_in[6];
    const float* Wc  = (const float*)d_in[7];
    const float* bc  = (const float*)d_in[8];
    float* out = (float*)d_out;

    const size_t szA = (size_t)8192 * 4096 * 2;   // 64 MiB bf16 A
    const size_t szW = (size_t)3072 * 4096 * 2;   // 24 MiB bf16 W
    const size_t szG = (size_t)8192 * 3072 * 2;   // 48 MiB bf16 gates

    if (ws_size >= szA + szW + szG) {
        USHORT* Abf = (USHORT*)d_ws;
        USHORT* Wbf = (USHORT*)((char*)d_ws + szA);
        USHORT* Gbf = (USHORT*)((char*)d_ws + szA + szW);
        conv_all<<<16384 + 6144, 256, 0, stream>>>(h, x, glo, Wi, Wf, Wc, Abf, Wbf);
        gemm_bt<<<dim3(24, 64), 256, 0, stream>>>(Abf, Wbf, bi, bfp, bc, Gbf);
        epi<<<4096, 256, 0, stream>>>(Gbf, h, out);
    } else {
        gemm3_noconv<<<dim3(8, 64), 256, 0, stream>>>(
            h, x, glo, Wi, Wf, Wc, bi, bfp, bc, out);
    }
}